// Round 1
// baseline (1311.535 us; speedup 1.0000x reference)
//
#include <hip/hip_runtime.h>

#define B_SZ   65536
#define IN_SZ  256
#define H_SZ   512
#define K_SZ   768          // IN + H
#define BM     128
#define BN     128
#define BK     64
#define LDK    72           // padded LDS K-stride (elems); 144 B rows -> 16B aligned, 2-way banks

typedef __attribute__((ext_vector_type(4))) float  f32x4;
typedef __attribute__((ext_vector_type(8))) __bf16 bf16x8;

__device__ __forceinline__ unsigned short f2bf(float f) {
    unsigned u = __float_as_uint(f);
    u += 0x7FFFu + ((u >> 16) & 1u);      // round-to-nearest-even
    return (unsigned short)(u >> 16);
}

__device__ __forceinline__ float tanh_fast(float x) {
    x = fminf(fmaxf(x, -16.0f), 16.0f);   // avoid inf/inf; tanh saturates to 1.0f well before 16
    float e = __expf(2.0f * x);
    return (e - 1.0f) / (e + 1.0f);
}

// Build Wt[1024][768] bf16, k-major ("B^T input"): rows 0..511 = f-set cols, 512..1023 = c-set cols.
__global__ void prep_weights(const float* __restrict__ w_f, const float* __restrict__ w_c,
                             const float* __restrict__ r_f, const float* __restrict__ r_c,
                             unsigned short* __restrict__ wt) {
    int id = blockIdx.x * 256 + threadIdx.x;      // 0 .. 1024*768-1
    int n  = id / K_SZ;
    int k  = id - n * K_SZ;
    int col = n & (H_SZ - 1);
    float v;
    if (n < H_SZ) v = (k < IN_SZ) ? w_f[k * H_SZ + col] : r_f[(k - IN_SZ) * H_SZ + col];
    else          v = (k < IN_SZ) ? w_c[k * H_SZ + col] : r_c[(k - IN_SZ) * H_SZ + col];
    wt[(size_t)n * K_SZ + k] = f2bf(v);
}

__launch_bounds__(256, 2)
__global__ void smgu_kernel(const float* __restrict__ x, const float* __restrict__ h_prev,
                            const float* __restrict__ c_prev, const float* __restrict__ n_prev,
                            const float* __restrict__ m_prev,
                            const float* __restrict__ b_f, const float* __restrict__ b_c,
                            const unsigned short* __restrict__ wt,
                            float* __restrict__ out) {
    __shared__ unsigned short sA[BM * LDK];
    __shared__ unsigned short sF[BN * LDK];
    __shared__ unsigned short sC[BN * LDK];

    const int tid    = threadIdx.x;
    const int bid    = blockIdx.x;
    const int tile_m = bid >> 2;           // 512 row blocks
    const int tile_n = bid & 3;            // 4 col blocks over H
    const int m0 = tile_m * BM;
    const int n0 = tile_n * BN;            // H-column base

    const int lane = tid & 63;
    const int wave = tid >> 6;             // 4 waves, 2x2 grid of 64x64 sub-tiles
    const int wm = (wave >> 1) * 64;
    const int wn = (wave & 1) * 64;

    const int fr = lane & 15;              // fragment row/col within 16
    const int fg = (lane >> 4) * 8;        // k-octet offset

    f32x4 accF[4][4];
    f32x4 accC[4][4];
#pragma unroll
    for (int i = 0; i < 4; ++i)
#pragma unroll
        for (int j = 0; j < 4; ++j) { accF[i][j] = (f32x4)0.0f; accC[i][j] = (f32x4)0.0f; }

    for (int kb = 0; kb < K_SZ; kb += BK) {
        // ---- stage A (f32 -> bf16 in registers) : rows m0..m0+127, k kb..kb+63
        {
            const float* src; int ldsrc, kloc;
            if (kb < IN_SZ) { src = x;      ldsrc = IN_SZ; kloc = kb; }
            else            { src = h_prev; ldsrc = H_SZ;  kloc = kb - IN_SZ; }
#pragma unroll
            for (int j = 0; j < 8; ++j) {
                int idx = tid + 256 * j;          // 2048 float4 chunks
                int row = idx >> 4, c4 = idx & 15;
                const float4 v = *(const float4*)&src[(size_t)(m0 + row) * ldsrc + kloc + c4 * 4];
                ushort4 b;
                b.x = f2bf(v.x); b.y = f2bf(v.y); b.z = f2bf(v.z); b.w = f2bf(v.w);
                *(ushort4*)&sA[row * LDK + c4 * 4] = b;
            }
        }
        // ---- stage both weight tiles (already bf16 k-major in ws)
#pragma unroll
        for (int j = 0; j < 4; ++j) {
            int idx = tid + 256 * j;              // 1024 16B chunks per set
            int row = idx >> 3, c8 = idx & 7;
            uint4 vf = *(const uint4*)&wt[(size_t)(n0 + row) * K_SZ + kb + c8 * 8];
            *(uint4*)&sF[row * LDK + c8 * 8] = vf;
            uint4 vc = *(const uint4*)&wt[(size_t)(H_SZ + n0 + row) * K_SZ + kb + c8 * 8];
            *(uint4*)&sC[row * LDK + c8 * 8] = vc;
        }
        __syncthreads();

        // ---- MFMA over this K-chunk
#pragma unroll
        for (int ks = 0; ks < BK; ks += 32) {
            bf16x8 af[4], bf[4], bc[4];
#pragma unroll
            for (int mi = 0; mi < 4; ++mi)
                af[mi] = *(const bf16x8*)&sA[(wm + mi * 16 + fr) * LDK + ks + fg];
#pragma unroll
            for (int ni = 0; ni < 4; ++ni) {
                bf[ni] = *(const bf16x8*)&sF[(wn + ni * 16 + fr) * LDK + ks + fg];
                bc[ni] = *(const bf16x8*)&sC[(wn + ni * 16 + fr) * LDK + ks + fg];
            }
#pragma unroll
            for (int mi = 0; mi < 4; ++mi)
#pragma unroll
                for (int ni = 0; ni < 4; ++ni) {
                    accF[mi][ni] = __builtin_amdgcn_mfma_f32_16x16x32_bf16(af[mi], bf[ni], accF[mi][ni], 0, 0, 0);
                    accC[mi][ni] = __builtin_amdgcn_mfma_f32_16x16x32_bf16(af[mi], bc[ni], accC[mi][ni], 0, 0, 0);
                }
        }
        __syncthreads();
    }

    // ---- fused epilogue. C/D layout: col = lane&15, row = (lane>>4)*4 + reg  [m89/m91-verified]
    const size_t BH = (size_t)B_SZ * H_SZ;
#pragma unroll
    for (int ni = 0; ni < 4; ++ni) {
        int col = n0 + wn + ni * 16 + fr;
        float bfv = b_f[col], bcv = b_c[col];
#pragma unroll
        for (int mi = 0; mi < 4; ++mi) {
            int row0 = m0 + wm + mi * 16 + (lane >> 4) * 4;
#pragma unroll
            for (int r = 0; r < 4; ++r) {
                size_t idx = (size_t)(row0 + r) * H_SZ + col;
                float pre_f = accF[mi][ni][r] + bfv;
                float pre_c = accC[mi][ni][r] + bcv;
                float mp = m_prev[idx];
                float s  = pre_f + mp;
                float m_t = fmaxf(s, 0.0f);
                float ip  = __expf(-m_t);
                float fp  = __expf(s - m_t);
                float cp  = c_prev[idx];
                float np  = n_prev[idx];
                float c_t = fp * cp + ip * tanh_fast(pre_c);
                float n_t = fp * np + ip;
                float h_t = tanh_fast(c_t / fmaxf(n_t, 1e-8f));
                out[idx]          = h_t;
                out[BH + idx]     = c_t;
                out[2 * BH + idx] = n_t;
                out[3 * BH + idx] = m_t;
            }
        }
    }
}

extern "C" void kernel_launch(void* const* d_in, const int* in_sizes, int n_in,
                              void* d_out, int out_size, void* d_ws, size_t ws_size,
                              hipStream_t stream) {
    const float* x      = (const float*)d_in[0];
    const float* h_prev = (const float*)d_in[1];
    const float* c_prev = (const float*)d_in[2];
    const float* n_prev = (const float*)d_in[3];
    const float* m_prev = (const float*)d_in[4];
    const float* w_f    = (const float*)d_in[5];
    const float* w_c    = (const float*)d_in[6];
    const float* r_f    = (const float*)d_in[7];
    const float* r_c    = (const float*)d_in[8];
    const float* b_f    = (const float*)d_in[9];
    const float* b_c    = (const float*)d_in[10];
    float* out = (float*)d_out;
    unsigned short* wt = (unsigned short*)d_ws;   // 1024*768*2 = 1.5 MiB

    prep_weights<<<(2 * H_SZ * K_SZ) / 256, 256, 0, stream>>>(w_f, w_c, r_f, r_c, wt);
    smgu_kernel<<<(B_SZ / BM) * (H_SZ / BN), 256, 0, stream>>>(
        x, h_prev, c_prev, n_prev, m_prev, b_f, b_c, wt, out);
}